// Round 12
// baseline (251.070 us; speedup 1.0000x reference)
//
#include <hip/hip_runtime.h>
#include <hip/hip_bf16.h>
#include <stdint.h>
#include <stddef.h>

typedef __bf16 bf16_t;
typedef __bf16 bf16x8 __attribute__((ext_vector_type(8)));
typedef float  f32x4  __attribute__((ext_vector_type(4)));
typedef float  f32x16 __attribute__((ext_vector_type(16)));

#define NN 1024
#define H  128
#define GRID 2048   // 256-thr blocks; 8 consecutive 64-row tiles per block

// ---------------- f_i = node @ Wi^T, f_j = node @ Wj^T (fp32 out) + We->bf16 ----------------
__global__ void k_proj(const float* __restrict__ node,
                       const float* __restrict__ Wi,
                       const float* __restrict__ Wj,
                       const float* __restrict__ We,
                       float* __restrict__ fi,
                       float* __restrict__ fj,
                       bf16_t* __restrict__ web) {
    __shared__ float nrow[H];
    const int row = blockIdx.x;
    const int t   = threadIdx.x;
    const int h   = t & (H - 1);
    const int sel = t >> 7;

    // fused We conversion: blocks 0..63 cover all 16384 elements
    if (blockIdx.x < 64) {
        const int i = blockIdx.x * 256 + t;
        web[i] = (bf16_t)We[i];
    }

    if (t < H) nrow[t] = node[(size_t)row * H + t];
    __syncthreads();
    const float* w = (sel ? Wj : Wi) + (size_t)h * H;
    float acc = 0.f;
    #pragma unroll
    for (int k4 = 0; k4 < H / 4; ++k4) {
        f32x4 wv = *(const f32x4*)(w + k4 * 4);
        f32x4 nv = *(const f32x4*)(&nrow[k4 * 4]);
        acc += nv[0] * wv[0] + nv[1] * wv[1] + nv[2] * wv[2] + nv[3] * wv[3];
    }
    float* dst = sel ? fj : fi;
    dst[(size_t)row * H + h] = acc;
}

// ---------------- main: out = relu(edge @ We^T + be + f_i[i].f_j[j]) ----------------
// R11 structure with two changes:
//  (a) full 5-bit XOR swizzle ((row&31)<<4): frag ds_read_b128 now perfectly
//      bank-conflict-free (was 4-way with the 3-bit (row&7) swizzle: 32 lanes
//      -> 8 slots); staging-write stays 2-way (free).
//  (b) k_dots fused away: block b needs exactly ONE f_i row (i=b>>1) and 512
//      consecutive f_j rows (j0=(b&1)*512) -> prologue computes the 512 dots
//      in fp32 from L2-resident f_i/f_j (64 f32x4 loads + 256 FMA/thread).
__global__ __launch_bounds__(256)
void k_main(const float* __restrict__ edge,   // [1M][128] fp32
            const bf16_t* __restrict__ web,   // [128][128] bf16
            const float* __restrict__ be,     // [128]
            const float* __restrict__ fi,     // [1024][128] fp32
            const float* __restrict__ fj,     // [1024][128] fp32
            float* __restrict__ out) {        // [1M][128] fp32
    __shared__ __align__(16) float bufA[64][H];   // 32 KB
    __shared__ __align__(16) float bufB[64][H];   // 32 KB
    __shared__ float ldots[512];
    __shared__ __align__(16) float fish[H];

    const int t    = threadIdx.x;       // 0..255
    const int w    = t >> 6;            // wave 0..3
    const int lane = t & 63;
    const int l31  = lane & 31;
    const int h    = lane >> 5;
    const int wm   = w & 1;             // row half of tile
    const int wn   = w >> 1;            // col half of tile
    const size_t base = (size_t)blockIdx.x * 512;   // first edge row of block

    // ---- fused dots: fish = f_i[i], then 2 dots per thread into ldots ----
    const int ii = blockIdx.x >> 1;
    const int jb = (blockIdx.x & 1) << 9;
    if (t < 32) ((f32x4*)fish)[t] = ((const f32x4*)(fi + (size_t)ii * H))[t];
    __syncthreads();
    {
        const float* r0 = fj + (size_t)(jb + t) * H;
        const float* r1 = fj + (size_t)(jb + 256 + t) * H;
        float d0 = 0.f, d1 = 0.f;
        #pragma unroll
        for (int c = 0; c < 32; ++c) {
            f32x4 a0 = ((const f32x4*)r0)[c];
            f32x4 a1 = ((const f32x4*)r1)[c];
            f32x4 fv = ((const f32x4*)fish)[c];
            d0 += a0[0]*fv[0] + a0[1]*fv[1] + a0[2]*fv[2] + a0[3]*fv[3];
            d1 += a1[0]*fv[0] + a1[1]*fv[1] + a1[2]*fv[2] + a1[3]*fv[3];
        }
        ldots[t]       = d0;
        ldots[256 + t] = d1;
    }
    // visibility of ldots is covered by the LDS_BARRIER at loop top.

    // We fragments: B operand, col = wn*64 + nt*32 + l31, k = kk*16 + h*8 + e
    bf16x8 wfr[2][8];
    {
        const bf16_t* wp = web + (size_t)(wn * 64 + l31) * H + h * 8;
        #pragma unroll
        for (int nt = 0; nt < 2; ++nt)
            #pragma unroll
            for (int kk = 0; kk < 8; ++kk)
                wfr[nt][kk] = *(const bf16x8*)(wp + (size_t)(nt * 32) * H + kk * 16);
    }
    float bias[2];
    #pragma unroll
    for (int nt = 0; nt < 2; ++nt) bias[nt] = be[wn * 64 + nt * 32 + l31];

    // reg-staging: wave w covers rows [w*16, w*16+16) of each 64-row tile.
    // Contiguous 1KB per wave-instruction; 5-bit XOR involution per row.
    #define LOADT(K, V)                                                          \
        {                                                                        \
            const char* tb = (const char*)(edge + (base + (size_t)(K) * 64) * H); \
            _Pragma("unroll")                                                    \
            for (int i = 0; i < 8; ++i) {                                        \
                const int rr = w * 16 + 2 * i + h;                               \
                V[i] = *(const f32x4*)(tb + rr * 512 + ((l31 * 16) ^ ((rr & 31) << 4))); \
            }                                                                    \
        }
    #define WRITET(BUFP, V)                                                      \
        {                                                                        \
            _Pragma("unroll")                                                    \
            for (int i = 0; i < 8; ++i)                                          \
                *(f32x4*)((char*)&BUFP[w * 16 + 2 * i][0] + h * 512 + l31 * 16) = V[i]; \
        }

    // raw barrier: LDS visibility only, NO vmem drain
    #define LDS_BARRIER()                                                        \
        {                                                                        \
            __builtin_amdgcn_sched_barrier(0);                                   \
            asm volatile("s_waitcnt lgkmcnt(0)" ::: "memory");                   \
            __builtin_amdgcn_s_barrier();                                        \
            __builtin_amdgcn_sched_barrier(0);                                   \
        }

    {
        f32x4 v0[8];
        LOADT(0, v0)
        WRITET(bufA, v0)
    }

    const int sw = l31 << 4;   // frag-read swizzle: (row&31)<<4, row = wm*32+l31

    #pragma unroll 1
    for (int k = 0; k < 8; ++k) {
        LDS_BARRIER()   // tile k's ds_writes (and prologue ldots) visible

        // 1) issue next tile's global loads (in flight across MFMA+stores)
        f32x4 vn[8];
        if (k < 7) LOADT(k + 1, vn)

        // 2) fragment reads for tile k: A rows = wm*32 + l31, k = kk*16+h*8+e
        //    slot = (kk*4 + h*2 + {0,1}) ^ l31 -> 32 distinct slots: conflict-free
        const char* crow = (const char*)((k & 1) ? &bufB[0][0] : &bufA[0][0])
                         + (wm * 32 + l31) * 512;
        f32x4 ua[8], ub[8];
        #pragma unroll
        for (int kk = 0; kk < 8; ++kk) {
            ua[kk] = *(const f32x4*)(crow + ((kk * 64 + h * 32 +  0) ^ sw));
            ub[kk] = *(const f32x4*)(crow + ((kk * 64 + h * 32 + 16) ^ sw));
        }

        // 3) acc init = bias(col) + dots(row); row r = wm*32 + 4h + (reg&3) + 8*(reg>>2)
        f32x4 dv[4];
        #pragma unroll
        for (int b = 0; b < 4; ++b)
            dv[b] = *(const f32x4*)(&ldots[k * 64 + wm * 32 + 4 * h + 8 * b]);

        f32x16 acc[2];
        #pragma unroll
        for (int nt = 0; nt < 2; ++nt)
            #pragma unroll
            for (int r = 0; r < 16; ++r)
                acc[nt][r] = bias[nt] + dv[r >> 2][r & 3];

        #pragma unroll
        for (int kk = 0; kk < 8; ++kk) {
            bf16x8 af;
            #pragma unroll
            for (int e = 0; e < 4; ++e) {
                af[e]     = (bf16_t)ua[kk][e];
                af[e + 4] = (bf16_t)ub[kk][e];
            }
            #pragma unroll
            for (int nt = 0; nt < 2; ++nt)
                acc[nt] = __builtin_amdgcn_mfma_f32_32x32x16_bf16(af, wfr[nt][kk], acc[nt], 0, 0, 0);
        }

        // 4) nontemporal full-line stores (two 128B lines per instruction)
        float* orow = out + (base + (size_t)k * 64 + wm * 32 + 4 * h) * H + wn * 64 + l31;
        #pragma unroll
        for (int nt = 0; nt < 2; ++nt)
            #pragma unroll
            for (int r = 0; r < 16; ++r)
                __builtin_nontemporal_store(
                    fmaxf(acc[nt][r], 0.f),
                    &orow[((r & 3) + 8 * (r >> 2)) * H + nt * 32]);

        // 5) ds_write tile k+1 (counted vmcnt for vn; stores stay outstanding)
        if (k < 7) {
            if (k & 1) { WRITET(bufA, vn) }
            else       { WRITET(bufB, vn) }
        }
    }
    #undef LOADT
    #undef WRITET
    #undef LDS_BARRIER
}

extern "C" void kernel_launch(void* const* d_in, const int* in_sizes, int n_in,
                              void* d_out, int out_size, void* d_ws, size_t ws_size,
                              hipStream_t stream) {
    const float* node = (const float*)d_in[0];
    const float* edge = (const float*)d_in[1];
    const float* We   = (const float*)d_in[2];
    const float* be   = (const float*)d_in[3];
    const float* Wi   = (const float*)d_in[4];
    const float* Wj   = (const float*)d_in[5];
    float* out = (float*)d_out;

    char* w = (char*)d_ws;
    float*  fi_f  = (float*)w;                               // 512 KB
    float*  fj_f  = (float*)(w + (512 << 10));               // 512 KB
    bf16_t* web   = (bf16_t*)(w + (1 << 20));                // 32 KB

    k_proj<<<NN, 256, 0, stream>>>(node, Wi, Wj, We, fi_f, fj_f, web);
    k_main<<<GRID, 256, 0, stream>>>(edge, web, be, fi_f, fj_f, out);
}

// Round 13
// 226.185 us; speedup vs baseline: 1.1100x; 1.1100x over previous
//
#include <hip/hip_runtime.h>
#include <hip/hip_bf16.h>
#include <stdint.h>
#include <stddef.h>

typedef __bf16 bf16_t;
typedef __bf16 bf16x8 __attribute__((ext_vector_type(8)));
typedef float  f32x4  __attribute__((ext_vector_type(4)));
typedef float  f32x16 __attribute__((ext_vector_type(16)));

#define NN 1024
#define H  128
#define GRID 2048   // 256-thr blocks; 8 consecutive 64-row tiles per block

// ---------------- f_i = node @ Wi^T, f_j = node @ Wj^T (+ fused We->bf16) ----------------
__global__ void k_proj(const float* __restrict__ node,
                       const float* __restrict__ Wi,
                       const float* __restrict__ Wj,
                       const float* __restrict__ We,
                       bf16_t* __restrict__ fi,
                       bf16_t* __restrict__ fj,
                       bf16_t* __restrict__ web) {
    __shared__ float nrow[H];
    const int row = blockIdx.x;
    const int t   = threadIdx.x;
    const int h   = t & (H - 1);
    const int sel = t >> 7;

    // fused We conversion: blocks 0..63 cover all 16384 elements
    if (blockIdx.x < 64) {
        const int i = blockIdx.x * 256 + t;
        web[i] = (bf16_t)We[i];
    }

    if (t < H) nrow[t] = node[(size_t)row * H + t];
    __syncthreads();
    const float* w = (sel ? Wj : Wi) + (size_t)h * H;
    float acc = 0.f;
    #pragma unroll
    for (int k4 = 0; k4 < H / 4; ++k4) {
        f32x4 wv = *(const f32x4*)(w + k4 * 4);
        f32x4 nv = *(const f32x4*)(&nrow[k4 * 4]);
        acc += nv[0] * wv[0] + nv[1] * wv[1] + nv[2] * wv[2] + nv[3] * wv[3];
    }
    bf16_t* dst = sel ? fj : fi;
    dst[(size_t)row * H + h] = (bf16_t)acc;
}

// ---------------- dots[i][j] = f_i[i] . f_j[j]  (grid 128: 16x8 tiles of 64x128) ----------------
__global__ __launch_bounds__(256, 4)
void k_dots(const bf16_t* __restrict__ fi,
            const bf16_t* __restrict__ fj,
            float* __restrict__ dots) {
    const int t    = threadIdx.x;
    const int wave = t >> 6;
    const int lane = t & 63;
    const int l15  = lane & 15;
    const int g    = lane >> 4;

    const int bm    = blockIdx.x >> 3;
    const int bn    = blockIdx.x & 7;
    const int ibase = bm * 64 + wave * 16;
    const int jbase = bn * 128;

    f32x4 acc[8];
    #pragma unroll
    for (int nt = 0; nt < 8; ++nt) acc[nt] = (f32x4){0.f, 0.f, 0.f, 0.f};

    const bf16_t* a = fi + (size_t)(ibase + l15) * H + g * 8;

    #pragma unroll
    for (int kst = 0; kst < 4; ++kst) {
        bf16x8 af = *(const bf16x8*)(a + kst * 32);
        #pragma unroll
        for (int nt = 0; nt < 8; ++nt) {
            bf16x8 bf = *(const bf16x8*)(fj + (size_t)(jbase + nt * 16 + l15) * H + kst * 32 + g * 8);
            acc[nt] = __builtin_amdgcn_mfma_f32_16x16x32_bf16(af, bf, acc[nt], 0, 0, 0);
        }
    }

    const int rbase = ibase + g * 4;
    #pragma unroll
    for (int r = 0; r < 4; ++r)
        #pragma unroll
        for (int nt = 0; nt < 8; ++nt)
            dots[(size_t)(rbase + r) * NN + jbase + nt * 16 + l15] = acc[nt][r];
}

// ---------------- main: out = relu(edge @ We^T + be + dots[row]) ----------------
// R11 structure (best known: 235.3us) with two isolated read-side tweaks:
//  (a) 5-bit XOR swizzle ((row&31)<<4): frag ds_read_b128 conflict-free
//      (R11's 3-bit left a 4-way conflict);
//  (b) NONTEMPORAL staging loads: edge is streamed exactly once -> mark
//      lines non-allocating to cut L2/L3 read-allocate pressure.
__global__ __launch_bounds__(256)
void k_main(const float* __restrict__ edge,   // [1M][128] fp32
            const bf16_t* __restrict__ web,   // [128][128] bf16
            const float* __restrict__ be,     // [128]
            const float* __restrict__ dots,   // [1M]
            float* __restrict__ out) {        // [1M][128] fp32
    __shared__ __align__(16) float bufA[64][H];   // 32 KB
    __shared__ __align__(16) float bufB[64][H];   // 32 KB
    __shared__ float ldots[512];

    const int t    = threadIdx.x;       // 0..255
    const int w    = t >> 6;            // wave 0..3
    const int lane = t & 63;
    const int l31  = lane & 31;
    const int h    = lane >> 5;
    const int wm   = w & 1;             // row half of tile
    const int wn   = w >> 1;            // col half of tile
    const size_t base = (size_t)blockIdx.x * 512;   // first edge row of block

    // dots for the block's 512 rows -> LDS
    ldots[t]       = dots[base + t];
    ldots[256 + t] = dots[base + 256 + t];

    // We fragments: B operand, col = wn*64 + nt*32 + l31, k = kk*16 + h*8 + e
    bf16x8 wfr[2][8];
    {
        const bf16_t* wp = web + (size_t)(wn * 64 + l31) * H + h * 8;
        #pragma unroll
        for (int nt = 0; nt < 2; ++nt)
            #pragma unroll
            for (int kk = 0; kk < 8; ++kk)
                wfr[nt][kk] = *(const bf16x8*)(wp + (size_t)(nt * 32) * H + kk * 16);
    }
    float bias[2];
    #pragma unroll
    for (int nt = 0; nt < 2; ++nt) bias[nt] = be[wn * 64 + nt * 32 + l31];

    // reg-staging: wave w covers rows [w*16, w*16+16) of each 64-row tile.
    // Contiguous 1KB per wave-instruction; 5-bit XOR involution per row;
    // nontemporal (stream-once, no L2/L3 allocate).
    #define LOADT(K, V)                                                          \
        {                                                                        \
            const char* tb = (const char*)(edge + (base + (size_t)(K) * 64) * H); \
            _Pragma("unroll")                                                    \
            for (int i = 0; i < 8; ++i) {                                        \
                const int rr = w * 16 + 2 * i + h;                               \
                V[i] = __builtin_nontemporal_load(                               \
                    (const f32x4*)(tb + rr * 512 + ((l31 * 16) ^ ((rr & 31) << 4)))); \
            }                                                                    \
        }
    #define WRITET(BUFP, V)                                                      \
        {                                                                        \
            _Pragma("unroll")                                                    \
            for (int i = 0; i < 8; ++i)                                          \
                *(f32x4*)((char*)&BUFP[w * 16 + 2 * i][0] + h * 512 + l31 * 16) = V[i]; \
        }

    // raw barrier: LDS visibility only, NO vmem drain
    #define LDS_BARRIER()                                                        \
        {                                                                        \
            __builtin_amdgcn_sched_barrier(0);                                   \
            asm volatile("s_waitcnt lgkmcnt(0)" ::: "memory");                   \
            __builtin_amdgcn_s_barrier();                                        \
            __builtin_amdgcn_sched_barrier(0);                                   \
        }

    {
        f32x4 v0[8];
        LOADT(0, v0)
        WRITET(bufA, v0)
    }

    const int sw = l31 << 4;   // frag-read swizzle: (row&31)<<4, row = wm*32+l31

    #pragma unroll 1
    for (int k = 0; k < 8; ++k) {
        LDS_BARRIER()   // tile k's ds_writes visible; prior readers done

        // 1) issue next tile's global loads (in flight across MFMA+stores)
        f32x4 vn[8];
        if (k < 7) LOADT(k + 1, vn)

        // 2) fragment reads for tile k: A rows = wm*32 + l31, k = kk*16+h*8+e
        //    slot = (kk*4 + h*2 + {0,1}) ^ l31 -> 32 distinct slots/wave: conflict-free
        const char* crow = (const char*)((k & 1) ? &bufB[0][0] : &bufA[0][0])
                         + (wm * 32 + l31) * 512;
        f32x4 ua[8], ub[8];
        #pragma unroll
        for (int kk = 0; kk < 8; ++kk) {
            ua[kk] = *(const f32x4*)(crow + ((kk * 64 + h * 32 +  0) ^ sw));
            ub[kk] = *(const f32x4*)(crow + ((kk * 64 + h * 32 + 16) ^ sw));
        }

        // 3) acc init = bias(col) + dots(row); row r = wm*32 + 4h + (reg&3) + 8*(reg>>2)
        f32x4 dv[4];
        #pragma unroll
        for (int b = 0; b < 4; ++b)
            dv[b] = *(const f32x4*)(&ldots[k * 64 + wm * 32 + 4 * h + 8 * b]);

        f32x16 acc[2];
        #pragma unroll
        for (int nt = 0; nt < 2; ++nt)
            #pragma unroll
            for (int r = 0; r < 16; ++r)
                acc[nt][r] = bias[nt] + dv[r >> 2][r & 3];

        #pragma unroll
        for (int kk = 0; kk < 8; ++kk) {
            bf16x8 af;
            #pragma unroll
            for (int e = 0; e < 4; ++e) {
                af[e]     = (bf16_t)ua[kk][e];
                af[e + 4] = (bf16_t)ub[kk][e];
            }
            #pragma unroll
            for (int nt = 0; nt < 2; ++nt)
                acc[nt] = __builtin_amdgcn_mfma_f32_32x32x16_bf16(af, wfr[nt][kk], acc[nt], 0, 0, 0);
        }

        // 4) nontemporal full-line stores (two 128B lines per instruction)
        float* orow = out + (base + (size_t)k * 64 + wm * 32 + 4 * h) * H + wn * 64 + l31;
        #pragma unroll
        for (int nt = 0; nt < 2; ++nt)
            #pragma unroll
            for (int r = 0; r < 16; ++r)
                __builtin_nontemporal_store(
                    fmaxf(acc[nt][r], 0.f),
                    &orow[((r & 3) + 8 * (r >> 2)) * H + nt * 32]);

        // 5) ds_write tile k+1 (counted vmcnt for vn; stores stay outstanding)
        if (k < 7) {
            if (k & 1) { WRITET(bufA, vn) }
            else       { WRITET(bufB, vn) }
        }
    }
    #undef LOADT
    #undef WRITET
    #undef LDS_BARRIER
}

extern "C" void kernel_launch(void* const* d_in, const int* in_sizes, int n_in,
                              void* d_out, int out_size, void* d_ws, size_t ws_size,
                              hipStream_t stream) {
    const float* node = (const float*)d_in[0];
    const float* edge = (const float*)d_in[1];
    const float* We   = (const float*)d_in[2];
    const float* be   = (const float*)d_in[3];
    const float* Wi   = (const float*)d_in[4];
    const float* Wj   = (const float*)d_in[5];
    float* out = (float*)d_out;

    char* w = (char*)d_ws;
    bf16_t* fi_bf = (bf16_t*)w;                              // 256 KB
    bf16_t* fj_bf = (bf16_t*)(w + (256 << 10));              // 256 KB
    float*  dots  = (float*)(w + (512 << 10));               // 4 MB
    bf16_t* web   = (bf16_t*)(w + (512 << 10) + (4 << 20));  // 32 KB

    k_proj<<<NN, 256, 0, stream>>>(node, Wi, Wj, We, fi_bf, fj_bf, web);
    k_dots<<<128, 256, 0, stream>>>(fi_bf, fj_bf, dots);
    k_main<<<GRID, 256, 0, stream>>>(edge, web, be, dots, out);
}